// Round 4
// baseline (546.338 us; speedup 1.0000x reference)
//
#include <hip/hip_runtime.h>
#include <hip/hip_fp16.h>
#include <float.h>

#define MKEY 256        // K (key size)
#define NMEM 100000     // memory rows
#define NPAD 100096     // 782 * 128
#define NQ   2048       // queries
#define BM 128
#define BN 128
#define NTILES 782      // NPAD / BN
#define NGROUP 6256     // NPAD / 16 : 16-key screen groups
#define MTILES 16       // NQ / BM
#define GRID (128 * 98) // XCD-clustered id space; ntile>=782 early-exits
#define KEYBLOCKS (NPAD / 4)   // 25024
#define QS (127.0f / 6.0f)     // i8 quant scale (data ~N(0,1), clamp at 6 sigma)
#define SS2 ((6.0f / 127.0f) * (6.0f / 127.0f))  // dequant: dot_f = dot_i8 * SS2

typedef int i32x4 __attribute__((ext_vector_type(4)));

__device__ inline void gll16(const void* g, void* l) {
  __builtin_amdgcn_global_load_lds(
      (const __attribute__((address_space(1))) unsigned*)g,
      (__attribute__((address_space(3))) unsigned*)l, 16, 0, 0);
}

__device__ inline int pack_i8x4(float4 v) {
  int c0 = max(-127, min(127, __float2int_rn(v.x * QS)));
  int c1 = max(-127, min(127, __float2int_rn(v.y * QS)));
  int c2 = max(-127, min(127, __float2int_rn(v.z * QS)));
  int c3 = max(-127, min(127, __float2int_rn(v.w * QS)));
  return (c0 & 255) | ((c1 & 255) << 8) | ((c2 & 255) << 16) | ((c3 & 255) << 24);
}

// merged: keys fp32 -> i8 + inv key norm (fp32-exact) in blocks 0..25023;
// queries fp32 -> i8 in blocks 25024..25535
__global__ void convert(const float* __restrict__ q, const float* __restrict__ mem,
                        int* __restrict__ qi, int* __restrict__ ki,
                        float* __restrict__ rkn) {
  const int b = blockIdx.x;
  if (b >= KEYBLOCKS) {
    const int i = (b - KEYBLOCKS) * 256 + threadIdx.x;   // int4-group index
    const float4 v = *(const float4*)&q[(size_t)i * 4];
    qi[i] = pack_i8x4(v);
    return;
  }
  const int t = threadIdx.x, lane = t & 63, w = t >> 6;
  const int row = b * 4 + w;
  if (row < NMEM) {
    const float4 v = *(const float4*)&mem[(long)row * 512 + lane * 4];
    const float ss0 = v.x * v.x + v.y * v.y + v.z * v.z + v.w * v.w;
    ki[(size_t)row * 64 + lane] = pack_i8x4(v);
    float ss = ss0;
#pragma unroll
    for (int off = 32; off >= 1; off >>= 1) ss += __shfl_xor(ss, off, 64);
    if (lane == 0) rkn[row] = 1.0f / sqrtf(fmaxf(ss, 1e-30f));
  } else {
    ki[(size_t)row * 64 + lane] = 0;
    if (lane == 0) rkn[row] = 0.f;
  }
}

// Pass 1: i8 screening GEMM (mfma_i32_16x16x64_i8). 128x128 tile, 4 waves,
// 4 blocks/CU. Chunk-XOR swizzle pre-applied to gll16 source (rule #21).
// Epilogue: per-(query, 16-key-group) max, written QUERY-MAJOR:
// bmax16Q[qid * NGROUP + ntile*8 + gl]  (8 contiguous floats = 32 B per
// query per block -> rescore's scan is fully contiguous, no transpose pass).
__global__ __launch_bounds__(256, 4) void gemm_screen(
    const int* __restrict__ qi, const int* __restrict__ ki,
    const float* __restrict__ rkn, float* __restrict__ bmax16Q) {
  __shared__ __align__(128) char Ab[BM * 128];   // 128 rows x 128 i8 (one K-step)
  __shared__ __align__(128) char Bb[BN * 128];
  __shared__ float cand16[BM][9];                // [qrow][group 0..7], pad->no conflict

  // XCD-clustered decode: same-ntile blocks land on the same XCD (ids = mod 8)
  const int id = blockIdx.x;
  const int mtile = (id >> 3) & 15;
  const int ntile = (id & 7) + 8 * (id >> 7);
  if (ntile >= NTILES) return;

  const int t = threadIdx.x;
  const int w = t >> 6;
  const int lane = t & 63;
  const int wr = w >> 1, wc = w & 1;
  const int q16 = lane >> 4, l16 = lane & 15;
  const int l8 = lane >> 3, c8 = lane & 7;

  // staging: waves 0,1 -> Ab; waves 2,3 -> Bb; each wave 64 rows = 8 gll16.
  const int swz = (c8 ^ l8) * 16;
  int soff[8];
#pragma unroll
  for (int c = 0; c < 8; ++c)
    soff[c] = ((w & 1) * 64 + c * 8 + l8) * 256 + swz;   // bytes (row stride 256B)
  const char* asrc = (const char*)((w < 2) ? qi : ki) +
                     (size_t)(((w < 2) ? mtile : ntile) * 128) * 256;
  char* adst = ((w < 2) ? Ab : Bb) + (w & 1) * 8192;

  i32x4 acc[4][4];
#pragma unroll
  for (int i = 0; i < 4; i++)
#pragma unroll
    for (int j = 0; j < 4; j++) acc[i][j] = (i32x4){0, 0, 0, 0};

  // phys chunk per ks: logical chunk = ks*4 + q16, xor row&7 = l16&7
  int pc[2];
#pragma unroll
  for (int ks = 0; ks < 2; ++ks) pc[ks] = (((ks * 4 + q16) ^ (l16 & 7))) * 16;

#pragma unroll
  for (int s = 0; s < 2; ++s) {            // 2 K-steps of 128
    __syncthreads();
#pragma unroll
    for (int c = 0; c < 8; ++c)
      gll16(asrc + s * 128 + soff[c], adst + c * 1024);
    __syncthreads();
#pragma unroll
    for (int ks = 0; ks < 2; ++ks) {
      i32x4 av[4], bv[4];
#pragma unroll
      for (int i = 0; i < 4; i++)
        av[i] = *(const i32x4*)&Ab[(64 * wr + 16 * i + l16) * 128 + pc[ks]];
#pragma unroll
      for (int j = 0; j < 4; j++)
        bv[j] = *(const i32x4*)&Bb[(64 * wc + 16 * j + l16) * 128 + pc[ks]];
#pragma unroll
      for (int i = 0; i < 4; i++)
#pragma unroll
        for (int j = 0; j < 4; j++)
          acc[i][j] = __builtin_amdgcn_mfma_i32_16x16x64_i8(av[i], bv[j], acc[i][j], 0, 0, 0);
    }
  }

  // Epilogue: per-(query-row, 16-key-group) max of (i32 dot * S^2) * (1/kn).
  // Group gl = wc*4 + j covers key cols ntile*128 + gl*16 + l16.
  float rk[4];
#pragma unroll
  for (int j = 0; j < 4; j++) {
    const int ncol = ntile * BN + 64 * wc + 16 * j + l16;
    rk[j] = (ncol < NMEM) ? rkn[ncol] * SS2 : 0.f;
  }
#pragma unroll
  for (int i = 0; i < 4; i++) {
#pragma unroll
    for (int j = 0; j < 4; j++) {
#pragma unroll
      for (int r = 0; r < 4; r++) {
        float m = (float)acc[i][j][r] * rk[j];   // padded cols: exactly 0.0
#pragma unroll
        for (int off = 1; off < 16; off <<= 1)
          m = fmaxf(m, __shfl_xor(m, off, 64));
        if (l16 == 0) cand16[64 * wr + 16 * i + 4 * q16 + r][wc * 4 + j] = m;
      }
    }
  }
  __syncthreads();
  if (t < BM) {
    float4 v0, v1;
    v0.x = cand16[t][0]; v0.y = cand16[t][1]; v0.z = cand16[t][2]; v0.w = cand16[t][3];
    v1.x = cand16[t][4]; v1.y = cand16[t][5]; v1.z = cand16[t][6]; v1.w = cand16[t][7];
    float* dst = &bmax16Q[(size_t)(mtile * BM + t) * NGROUP + ntile * 8];
    *(float4*)dst = v0;          // 32-B aligned (NGROUP%8==0, ntile*8%8==0)
    *(float4*)(dst + 4) = v1;
  }
}

// Pass 2 per query (1 block):
//   A) contiguous scan of bmax16Q[qid][0..NGROUP) -> gm, thresh = gm - margin;
//      second scan collects candidate 16-row groups (~2.0 expected)
//   B) exact fp64 cosine for all rows of candidate groups (4 lanes/row,
//      16 rows per wave-pass); argmax with low-index tie-break
// margin 1.8e-2*qn = 14.9 sigma of the i8 score error >= 2 x 6.2-sigma bound;
// group-max >= shat(r*) >= gm - 2E, so the true argmax group always qualifies.
__global__ __launch_bounds__(256) void rescore_gather(
    const float* __restrict__ q, const float* __restrict__ mem,
    const float* __restrict__ bmax16Q, float* __restrict__ out) {
  __shared__ float red2[4];
  __shared__ int glist[64];
  __shared__ int ng;
  __shared__ double wb[4];
  __shared__ int wbi[4];
  __shared__ int widx;

  const int qid = blockIdx.x;
  const int t = threadIdx.x, w = t >> 6, lane = t & 63;

  // ||q|| from this lane's 4 dims
  const float4 qv = *(const float4*)&q[(size_t)qid * 256 + lane * 4];
  float ss = qv.x * qv.x + qv.y * qv.y + qv.z * qv.z + qv.w * qv.w;
#pragma unroll
  for (int off = 32; off >= 1; off >>= 1) ss += __shfl_xor(ss, off, 64);
  const float qn = sqrtf(ss);
  const float margin = 1.8e-2f * qn;

  if (t == 0) ng = 0;
  const float* bq = &bmax16Q[(size_t)qid * NGROUP];

  // ---- A: contiguous scan for gm ----
  float gm = -FLT_MAX;
  for (int i = t; i < NGROUP; i += 256) gm = fmaxf(gm, bq[i]);
#pragma unroll
  for (int off = 32; off >= 1; off >>= 1) gm = fmaxf(gm, __shfl_xor(gm, off, 64));
  if (lane == 0) red2[w] = gm;
  __syncthreads();
  gm = fmaxf(fmaxf(red2[0], red2[1]), fmaxf(red2[2], red2[3]));
  const float thresh = gm - margin;

  for (int i = t; i < NGROUP; i += 256)
    if (bq[i] >= thresh) {
      int p = atomicAdd(&ng, 1);
      if (p < 64) glist[p] = i;
    }
  __syncthreads();
  const int ng_ = min(ng, 64);

  // ---- B: exact fp64 cosine, 4 lanes per row, 16 rows per wave-pass ----
  const int rig = lane >> 2;        // row in group 0..15
  const int chk = lane & 3;         // 64-float chunk 0..3
  double bestv = -1e300;
  int bestidx = 0x7fffffff;
  for (int c = w; c < ng_; c += 4) {
    const int row = glist[c] * 16 + rig;
    double d = 0.0, s2 = 0.0;
    if (row < NMEM) {
#pragma unroll
      for (int k = 0; k < 16; ++k) {
        const float4 kv = *(const float4*)&mem[(size_t)row * 512 + chk * 64 + k * 4];
        d += (double)kv.x * q[(size_t)qid * 256 + chk * 64 + k * 4 + 0] +
             (double)kv.y * q[(size_t)qid * 256 + chk * 64 + k * 4 + 1] +
             (double)kv.z * q[(size_t)qid * 256 + chk * 64 + k * 4 + 2] +
             (double)kv.w * q[(size_t)qid * 256 + chk * 64 + k * 4 + 3];
        s2 += (double)kv.x * kv.x + (double)kv.y * kv.y +
              (double)kv.z * kv.z + (double)kv.w * kv.w;
      }
    }
    d += __shfl_xor(d, 1, 64);  d += __shfl_xor(d, 2, 64);
    s2 += __shfl_xor(s2, 1, 64); s2 += __shfl_xor(s2, 2, 64);
    if (chk == 0 && row < NMEM) {
      const double score = d / sqrt(s2 > 1e-300 ? s2 : 1e-300);
      if (score > bestv || (score == bestv && row < bestidx)) {
        bestv = score;
        bestidx = row;
      }
    }
  }
  // cross-lane argmax (lanes with chk!=0 hold -1e300)
#pragma unroll
  for (int off = 1; off < 64; off <<= 1) {
    const double ov = __shfl_xor(bestv, off, 64);
    const int oi = __shfl_xor(bestidx, off, 64);
    if (ov > bestv || (ov == bestv && oi < bestidx)) {
      bestv = ov;
      bestidx = oi;
    }
  }
  if (lane == 0) { wb[w] = bestv; wbi[w] = bestidx; }
  __syncthreads();
  if (t == 0) {
    double bv = wb[0];
    int bi = wbi[0];
#pragma unroll
    for (int w2 = 1; w2 < 4; ++w2)
      if (wb[w2] > bv || (wb[w2] == bv && wbi[w2] < bi)) {
        bv = wb[w2];
        bi = wbi[w2];
      }
    widx = bi;
  }
  __syncthreads();
  out[(size_t)qid * 256 + t] = mem[(size_t)widx * 512 + 256 + t];
}

extern "C" void kernel_launch(void* const* d_in, const int* in_sizes, int n_in,
                              void* d_out, int out_size, void* d_ws, size_t ws_size,
                              hipStream_t stream) {
  const float* query = (const float*)d_in[0];
  const float* memory = (const float*)d_in[1];
  float* out = (float*)d_out;

  char* p = (char*)d_ws;
  int* qi = (int*)p; p += (size_t)NQ * 64 * 4;             // 2048 x 256 i8
  int* ki = (int*)p; p += (size_t)NPAD * 64 * 4;           // 100096 x 256 i8
  float* rkn = (float*)p; p += (size_t)NPAD * 4;
  float* bmax16Q = (float*)p; p += (size_t)NQ * NGROUP * 4; // 51.25 MB

  hipLaunchKernelGGL(convert, dim3(KEYBLOCKS + NQ * MKEY / 1024), dim3(256), 0, stream,
                     query, memory, qi, ki, rkn);
  hipLaunchKernelGGL(gemm_screen, dim3(GRID), dim3(256), 0, stream, qi, ki, rkn, bmax16Q);
  hipLaunchKernelGGL(rescore_gather, dim3(NQ), dim3(256), 0, stream,
                     query, memory, bmax16Q, out);
}

// Round 5
// 401.244 us; speedup vs baseline: 1.3616x; 1.3616x over previous
//
#include <hip/hip_runtime.h>
#include <hip/hip_fp16.h>
#include <float.h>

#define MKEY 256        // K (key size)
#define NMEM 100000     // memory rows
#define NPAD 100096     // 782 * 128
#define NQ   2048       // queries
#define BM 128
#define BN 128
#define NTILES 782      // NPAD / BN : 128-row blocks
#define BLKPAD 800      // padded row stride for bmaxQ
#define NGROUP 6256     // NPAD / 16 : 16-key screen groups
#define MTILES 16       // NQ / BM
#define GRID (128 * 98) // XCD-clustered id space; ntile>=782 early-exits
#define KEYBLOCKS (NPAD / 4)   // 25024
#define QS (127.0f / 6.0f)     // i8 quant scale (data ~N(0,1), clamp at 6 sigma)
#define SS2 ((6.0f / 127.0f) * (6.0f / 127.0f))  // dequant: dot_f = dot_i8 * SS2

typedef int i32x4 __attribute__((ext_vector_type(4)));

__device__ inline void gll16(const void* g, void* l) {
  __builtin_amdgcn_global_load_lds(
      (const __attribute__((address_space(1))) unsigned*)g,
      (__attribute__((address_space(3))) unsigned*)l, 16, 0, 0);
}

__device__ inline int pack_i8x4(float4 v) {
  int c0 = max(-127, min(127, __float2int_rn(v.x * QS)));
  int c1 = max(-127, min(127, __float2int_rn(v.y * QS)));
  int c2 = max(-127, min(127, __float2int_rn(v.z * QS)));
  int c3 = max(-127, min(127, __float2int_rn(v.w * QS)));
  return (c0 & 255) | ((c1 & 255) << 8) | ((c2 & 255) << 16) | ((c3 & 255) << 24);
}

// merged: keys fp32 -> i8 + inv key norm (fp32-exact) in blocks 0..25023;
// queries fp32 -> i8 in blocks 25024..25535
__global__ void convert(const float* __restrict__ q, const float* __restrict__ mem,
                        int* __restrict__ qi, int* __restrict__ ki,
                        float* __restrict__ rkn) {
  const int b = blockIdx.x;
  if (b >= KEYBLOCKS) {
    const int i = (b - KEYBLOCKS) * 256 + threadIdx.x;   // int4-group index
    const float4 v = *(const float4*)&q[(size_t)i * 4];
    qi[i] = pack_i8x4(v);
    return;
  }
  const int t = threadIdx.x, lane = t & 63, w = t >> 6;
  const int row = b * 4 + w;
  if (row < NMEM) {
    const float4 v = *(const float4*)&mem[(long)row * 512 + lane * 4];
    const float ss0 = v.x * v.x + v.y * v.y + v.z * v.z + v.w * v.w;
    ki[(size_t)row * 64 + lane] = pack_i8x4(v);
    float ss = ss0;
#pragma unroll
    for (int off = 32; off >= 1; off >>= 1) ss += __shfl_xor(ss, off, 64);
    if (lane == 0) rkn[row] = 1.0f / sqrtf(fmaxf(ss, 1e-30f));
  } else {
    ki[(size_t)row * 64 + lane] = 0;
    if (lane == 0) rkn[row] = 0.f;
  }
}

// Pass 1: i8 screening GEMM (mfma_i32_16x16x64_i8). 128x128 tile, 4 waves,
// 4 blocks/CU. Chunk-XOR swizzle pre-applied to gll16 source (rule #21).
// Epilogue (LDS-based, no bpermute chains, coalesced stores):
//   bmax16T[(ntile*8+g)*NQ + qid] : per-16-key-group max, group-major
//   bmaxB  [ntile*NQ + qid]       : per-128-key-block max
__global__ __launch_bounds__(256, 4) void gemm_screen(
    const int* __restrict__ qi, const int* __restrict__ ki,
    const float* __restrict__ rkn,
    float* __restrict__ bmax16T, float* __restrict__ bmaxB) {
  // [0,16384) Ab, [16384,32768) Bb; epilogue overlays L (20480 B) on same
  // region after a barrier; bhalf lives above at [32768, 33792).
  __shared__ __align__(128) char smem[33792];
  char* const Ab = smem;
  char* const Bb = smem + 16384;

  // XCD-clustered decode: same-ntile blocks land on the same XCD (ids = mod 8)
  const int id = blockIdx.x;
  const int mtile = (id >> 3) & 15;
  const int ntile = (id & 7) + 8 * (id >> 7);
  if (ntile >= NTILES) return;

  const int t = threadIdx.x;
  const int w = t >> 6;
  const int lane = t & 63;
  const int wr = w >> 1, wc = w & 1;
  const int q16 = lane >> 4, l16 = lane & 15;
  const int l8 = lane >> 3, c8 = lane & 7;

  // staging: waves 0,1 -> Ab; waves 2,3 -> Bb; each wave 64 rows = 8 gll16.
  const int swz = (c8 ^ l8) * 16;
  int soff[8];
#pragma unroll
  for (int c = 0; c < 8; ++c)
    soff[c] = ((w & 1) * 64 + c * 8 + l8) * 256 + swz;   // bytes (row stride 256B)
  const char* asrc = (const char*)((w < 2) ? qi : ki) +
                     (size_t)(((w < 2) ? mtile : ntile) * 128) * 256;
  char* adst = ((w < 2) ? Ab : Bb) + (w & 1) * 8192;

  i32x4 acc[4][4];
#pragma unroll
  for (int i = 0; i < 4; i++)
#pragma unroll
    for (int j = 0; j < 4; j++) acc[i][j] = (i32x4){0, 0, 0, 0};

  // phys chunk per ks: logical chunk = ks*4 + q16, xor row&7 = l16&7
  int pc[2];
#pragma unroll
  for (int ks = 0; ks < 2; ++ks) pc[ks] = (((ks * 4 + q16) ^ (l16 & 7))) * 16;

#pragma unroll
  for (int s = 0; s < 2; ++s) {            // 2 K-steps of 128
    __syncthreads();
#pragma unroll
    for (int c = 0; c < 8; ++c)
      gll16(asrc + s * 128 + soff[c], adst + c * 1024);
    __syncthreads();
#pragma unroll
    for (int ks = 0; ks < 2; ++ks) {
      i32x4 av[4], bv[4];
#pragma unroll
      for (int i = 0; i < 4; i++)
        av[i] = *(const i32x4*)&Ab[(64 * wr + 16 * i + l16) * 128 + pc[ks]];
#pragma unroll
      for (int j = 0; j < 4; j++)
        bv[j] = *(const i32x4*)&Bb[(64 * wc + 16 * j + l16) * 128 + pc[ks]];
#pragma unroll
      for (int i = 0; i < 4; i++)
#pragma unroll
        for (int j = 0; j < 4; j++)
          acc[i][j] = __builtin_amdgcn_mfma_i32_16x16x64_i8(av[i], bv[j], acc[i][j], 0, 0, 0);
    }
  }

  // ---- Epilogue ----
  // rk per j (keys of group wc*4+j are cols ntile*128 + (wc*4+j)*16 + l16)
  float rk[4];
#pragma unroll
  for (int j = 0; j < 4; j++) {
    const int ncol = ntile * BN + 64 * wc + 16 * j + l16;
    rk[j] = (ncol < NMEM) ? rkn[ncol] * SS2 : 0.f;   // padded cols -> exactly 0.0
  }
  // L[(wr*8 + wc*4+j)*16 + (q16*4+r)][l16], pitch 20 floats (80 B, 16-B aligned)
  float (*L)[20] = (float(*)[20])smem;
  float* bhalf = (float*)(smem + 32768);   // [w][qrow][i] : 4*16*4 floats
  const int wr_ = t >> 7, gg = (t >> 4) & 7, qrow = t & 15;
  float outv[4];
  __syncthreads();   // all main-loop LDS reads retired before overlaying L
#pragma unroll
  for (int i = 0; i < 4; ++i) {
#pragma unroll
    for (int j = 0; j < 4; ++j)
#pragma unroll
      for (int r = 0; r < 4; ++r)
        L[(wr * 8 + wc * 4 + j) * 16 + q16 * 4 + r][l16] = (float)acc[i][j][r] * rk[j];
    __syncthreads();
    // each thread: max over 16 contiguous floats = one (row, group) pair
    const float* Lr = L[(wr_ * 8 + gg) * 16 + qrow];
    const float4 a = *(const float4*)&Lr[0], b4 = *(const float4*)&Lr[4];
    const float4 cc = *(const float4*)&Lr[8], dd = *(const float4*)&Lr[12];
    float m = fmaxf(fmaxf(fmaxf(a.x, a.y), fmaxf(a.z, a.w)),
                    fmaxf(fmaxf(b4.x, b4.y), fmaxf(b4.z, b4.w)));
    m = fmaxf(m, fmaxf(fmaxf(cc.x, cc.y), fmaxf(cc.z, cc.w)));
    m = fmaxf(m, fmaxf(fmaxf(dd.x, dd.y), fmaxf(dd.z, dd.w)));
    outv[i] = m;
    // block-max partial: reduce over this wave's 4 groups (lane bits 4,5)
    float bm = fmaxf(m, __shfl_xor(m, 16, 64));
    bm = fmaxf(bm, __shfl_xor(bm, 32, 64));
    if (lane < 16) bhalf[(w * 16 + lane) * 4 + i] = bm;
    __syncthreads();
  }
  // group table store: per wave 4 x 64-B coalesced segments per instr
#pragma unroll
  for (int i = 0; i < 4; ++i)
    bmax16T[(size_t)(ntile * 8 + gg) * NQ + mtile * 128 + wr_ * 64 + i * 16 + qrow] =
        outv[i];
  // block table store: coalesced 512 B
  if (t < 128) {
    const int wrb = t >> 6, ib = (t >> 4) & 3, qr = t & 15;
    const float v = fmaxf(bhalf[((2 * wrb) * 16 + qr) * 4 + ib],
                          bhalf[((2 * wrb + 1) * 16 + qr) * 4 + ib]);
    bmaxB[(size_t)ntile * NQ + mtile * 128 + t] = v;
  }
}

// bmaxB[782][2048] -> bmaxQ[2048][800] (pad cols 782..799 never read)
__global__ __launch_bounds__(256) void transpose_blk(const float* __restrict__ in,
                                                     float* __restrict__ outp) {
  __shared__ float tl[32][33];
  const int bid = blockIdx.x;
  const int ntt = bid % 25, qt = bid / 25;
  const int r0 = ntt * 32, c0 = qt * 32;
  const int tx = threadIdx.x & 31, ty = threadIdx.x >> 5;   // ty 0..7
#pragma unroll
  for (int k = 0; k < 4; ++k) {
    const int r = r0 + ty + 8 * k;
    tl[ty + 8 * k][tx] = (r < NTILES) ? in[(size_t)r * NQ + c0 + tx] : -FLT_MAX;
  }
  __syncthreads();
#pragma unroll
  for (int k = 0; k < 4; ++k) {
    const int qq = c0 + ty + 8 * k;
    const int nt = r0 + tx;
    if (nt < NTILES) outp[(size_t)qq * BLKPAD + nt] = tl[tx][ty + 8 * k];
  }
}

// Pass 2 per query (1 block), three-level funnel:
//   A) contiguous scan of bmaxQ[qid][0..782) -> gm; thresh = gm - margin;
//      candidate blocks (~2.5 expected)
//   B) read candidate blocks' 8 group-maxes from bmax16T -> candidate groups
//   C) exact fp64 cosine for rows of candidate groups; argmax, low-index ties
// margin 1.8e-2*qn = 14.9 sigma of i8 score error >= 2 x 6.2-sigma bound;
// block-max >= group-max >= shat(r*) >= gm - 2E, so truth always qualifies.
__global__ __launch_bounds__(256) void rescore_gather(
    const float* __restrict__ q, const float* __restrict__ mem,
    const float* __restrict__ bmaxQ, const float* __restrict__ bmax16T,
    float* __restrict__ out) {
  __shared__ float red2[4];
  __shared__ int blist[64];
  __shared__ int nblk;
  __shared__ int glist[64];
  __shared__ int ng;
  __shared__ double wb[4];
  __shared__ int wbi[4];
  __shared__ int widx;

  const int qid = blockIdx.x;
  const int t = threadIdx.x, w = t >> 6, lane = t & 63;

  // ||q|| from this lane's 4 dims
  const float4 qv = *(const float4*)&q[(size_t)qid * 256 + lane * 4];
  float ss = qv.x * qv.x + qv.y * qv.y + qv.z * qv.z + qv.w * qv.w;
#pragma unroll
  for (int off = 32; off >= 1; off >>= 1) ss += __shfl_xor(ss, off, 64);
  const float qn = sqrtf(ss);
  const float margin = 1.8e-2f * qn;

  if (t == 0) { nblk = 0; ng = 0; }
  const float* bq = &bmaxQ[(size_t)qid * BLKPAD];

  // ---- A: contiguous scan for gm ----
  float gm = -FLT_MAX;
  for (int i = t; i < NTILES; i += 256) gm = fmaxf(gm, bq[i]);
#pragma unroll
  for (int off = 32; off >= 1; off >>= 1) gm = fmaxf(gm, __shfl_xor(gm, off, 64));
  if (lane == 0) red2[w] = gm;
  __syncthreads();
  gm = fmaxf(fmaxf(red2[0], red2[1]), fmaxf(red2[2], red2[3]));
  const float thresh = gm - margin;

  for (int i = t; i < NTILES; i += 256)
    if (bq[i] >= thresh) {
      int p = atomicAdd(&nblk, 1);
      if (p < 64) blist[p] = i;
    }
  __syncthreads();
  const int nb_ = min(nblk, 64);

  // ---- B: candidate blocks -> candidate 16-row groups ----
  for (int idx = t; idx < nb_ * 8; idx += 256) {
    const int g = blist[idx >> 3] * 8 + (idx & 7);
    if (bmax16T[(size_t)g * NQ + qid] >= thresh) {
      int p = atomicAdd(&ng, 1);
      if (p < 64) glist[p] = g;
    }
  }
  __syncthreads();
  const int ng_ = min(ng, 64);

  // ---- C: exact fp64 cosine, 4 lanes per row, 16 rows per wave-pass ----
  const int rig = lane >> 2;        // row in group 0..15
  const int chk = lane & 3;         // 64-float chunk 0..3
  double bestv = -1e300;
  int bestidx = 0x7fffffff;
  for (int c = w; c < ng_; c += 4) {
    const int row = glist[c] * 16 + rig;
    double d = 0.0, s2 = 0.0;
    if (row < NMEM) {
#pragma unroll
      for (int k = 0; k < 16; ++k) {
        const float4 kv = *(const float4*)&mem[(size_t)row * 512 + chk * 64 + k * 4];
        d += (double)kv.x * q[(size_t)qid * 256 + chk * 64 + k * 4 + 0] +
             (double)kv.y * q[(size_t)qid * 256 + chk * 64 + k * 4 + 1] +
             (double)kv.z * q[(size_t)qid * 256 + chk * 64 + k * 4 + 2] +
             (double)kv.w * q[(size_t)qid * 256 + chk * 64 + k * 4 + 3];
        s2 += (double)kv.x * kv.x + (double)kv.y * kv.y +
              (double)kv.z * kv.z + (double)kv.w * kv.w;
      }
    }
    d += __shfl_xor(d, 1, 64);   d += __shfl_xor(d, 2, 64);
    s2 += __shfl_xor(s2, 1, 64); s2 += __shfl_xor(s2, 2, 64);
    if (chk == 0 && row < NMEM) {
      const double score = d / sqrt(s2 > 1e-300 ? s2 : 1e-300);
      if (score > bestv || (score == bestv && row < bestidx)) {
        bestv = score;
        bestidx = row;
      }
    }
  }
  // cross-lane argmax (lanes with chk!=0 hold -1e300)
#pragma unroll
  for (int off = 1; off < 64; off <<= 1) {
    const double ov = __shfl_xor(bestv, off, 64);
    const int oi = __shfl_xor(bestidx, off, 64);
    if (ov > bestv || (ov == bestv && oi < bestidx)) {
      bestv = ov;
      bestidx = oi;
    }
  }
  if (lane == 0) { wb[w] = bestv; wbi[w] = bestidx; }
  __syncthreads();
  if (t == 0) {
    double bv = wb[0];
    int bi = wbi[0];
#pragma unroll
    for (int w2 = 1; w2 < 4; ++w2)
      if (wb[w2] > bv || (wb[w2] == bv && wbi[w2] < bi)) {
        bv = wb[w2];
        bi = wbi[w2];
      }
    widx = bi;
  }
  __syncthreads();
  out[(size_t)qid * 256 + t] = mem[(size_t)widx * 512 + 256 + t];
}

extern "C" void kernel_launch(void* const* d_in, const int* in_sizes, int n_in,
                              void* d_out, int out_size, void* d_ws, size_t ws_size,
                              hipStream_t stream) {
  const float* query = (const float*)d_in[0];
  const float* memory = (const float*)d_in[1];
  float* out = (float*)d_out;

  char* p = (char*)d_ws;
  int* qi = (int*)p; p += (size_t)NQ * 64 * 4;               // 2 MB
  int* ki = (int*)p; p += (size_t)NPAD * 64 * 4;             // 25.6 MB
  float* rkn = (float*)p; p += (size_t)NPAD * 4;             // 0.4 MB
  float* bmaxB = (float*)p; p += (size_t)NTILES * NQ * 4;    // 6.4 MB
  float* bmaxQ = (float*)p; p += (size_t)NQ * BLKPAD * 4;    // 6.6 MB
  float* bmax16T = (float*)p; p += (size_t)NGROUP * NQ * 4;  // 51.3 MB

  hipLaunchKernelGGL(convert, dim3(KEYBLOCKS + NQ * MKEY / 1024), dim3(256), 0, stream,
                     query, memory, qi, ki, rkn);
  hipLaunchKernelGGL(gemm_screen, dim3(GRID), dim3(256), 0, stream,
                     qi, ki, rkn, bmax16T, bmaxB);
  hipLaunchKernelGGL(transpose_blk, dim3(25 * 64), dim3(256), 0, stream, bmaxB, bmaxQ);
  hipLaunchKernelGGL(rescore_gather, dim3(NQ), dim3(256), 0, stream,
                     query, memory, bmaxQ, bmax16T, out);
}